// Round 17
// baseline (984.434 us; speedup 1.0000x reference)
//
#include <hip/hip_runtime.h>
#include <hip/hip_bf16.h>
#include <math.h>

constexpr int NA  = 100000;
constexpr int NPP = 100000;
constexpr int D   = 128;
constexpr int H   = 4;
constexpr int E   = 400000;
constexpr int R   = 3;
constexpr int L   = 2;
constexpr int NSLOT = 23;
constexpr int SLOT_ELEMS = 8 * 4 * 512;   // 8 col-tiles * 4 ksteps * 512 bf16
constexpr int GB2c = (NA + 127) / 128;    // 782
constexpr int GAc  = NA / 8;              // 12500

using s8v = __attribute__((ext_vector_type(8))) short;
using f4v = __attribute__((ext_vector_type(4))) float;
typedef unsigned short ushort_t;

static __device__ __forceinline__ unsigned short f2bf(float f) {
  unsigned u = __float_as_uint(f);
  return (unsigned short)((u + 0x7fffu + ((u >> 16) & 1u)) >> 16);
}
static __device__ __forceinline__ float bf2f(unsigned short s) {
  return __uint_as_float(((unsigned)s) << 16);
}
static __device__ __forceinline__ float klo(int i) {        // low bf16 -> f32
  return __uint_as_float(((unsigned)i) << 16);
}
static __device__ __forceinline__ float vhi(int i) {        // high bf16 -> f32
  return __uint_as_float(((unsigned)i) & 0xffff0000u);
}
static __device__ __forceinline__ float gelu_f(float x) {
  return 0.5f * x * (1.0f + erff(x * 0.70710678118654752f));
}
static __device__ __forceinline__ float elu_f(float x) {
  return x > 0.0f ? x : expm1f(x);
}

// ============ device GEMM bodies (bf16 A, hi-only B, LDS-staged) ================
static __device__ __forceinline__ void load_a2(
    const ushort_t* __restrict__ A, int ar0, int ar1, int ks, int g,
    s8v& a0, s8v& a1) {
  const ushort_t* ap0 = A + (size_t)ar0 * 128 + ks * 32 + g * 4;
  ushort4 u0 = *(const ushort4*)ap0;
  ushort4 u1 = *(const ushort4*)(ap0 + 16);
  a0[0]=(short)u0.x; a0[1]=(short)u0.y; a0[2]=(short)u0.z; a0[3]=(short)u0.w;
  a0[4]=(short)u1.x; a0[5]=(short)u1.y; a0[6]=(short)u1.z; a0[7]=(short)u1.w;
  const ushort_t* ap1 = A + (size_t)ar1 * 128 + ks * 32 + g * 4;
  ushort4 v0 = *(const ushort4*)ap1;
  ushort4 v1 = *(const ushort4*)(ap1 + 16);
  a1[0]=(short)v0.x; a1[1]=(short)v0.y; a1[2]=(short)v0.z; a1[3]=(short)v0.w;
  a1[4]=(short)v1.x; a1[5]=(short)v1.y; a1[6]=(short)v1.z; a1[7]=(short)v1.w;
}

template<bool GELU_A, bool MIX>
__device__ __forceinline__ void dev_gemm8(
    const ushort_t* __restrict__ A, const ushort_t* __restrict__ Bhi,
    const float* __restrict__ bias, ushort_t* __restrict__ Cout,
    const float* __restrict__ skip_ptr, int M, int bx, ushort_t* Bs) {
  for (int i = threadIdx.x; i < 2048; i += 256)
    *(s8v*)&Bs[i * 8] = *(const s8v*)(Bhi + (size_t)i * 8);
  __syncthreads();
  const int lane = threadIdx.x & 63;
  const int wave = threadIdx.x >> 6;
  const int row0 = bx * 128 + wave * 32;
  const int g = lane >> 4, li = lane & 15;
  f4v acc0[8], acc1[8];
#pragma unroll
  for (int ct = 0; ct < 8; ++ct) {
    acc0[ct] = f4v{0.f, 0.f, 0.f, 0.f};
    acc1[ct] = f4v{0.f, 0.f, 0.f, 0.f};
  }
  int ar0 = row0 + li;       if (ar0 >= M) ar0 = M - 1;
  int ar1 = row0 + 16 + li;  if (ar1 >= M) ar1 = M - 1;
#pragma unroll
  for (int ks = 0; ks < 4; ++ks) {
    s8v a0, a1;
    load_a2(A, ar0, ar1, ks, g, a0, a1);
    if (GELU_A) {
#pragma unroll
      for (int i = 0; i < 8; ++i) {
        a0[i] = (short)f2bf(gelu_f(bf2f((unsigned short)a0[i])));
        a1[i] = (short)f2bf(gelu_f(bf2f((unsigned short)a1[i])));
      }
    }
#pragma unroll
    for (int ct = 0; ct < 8; ++ct) {
      s8v bhi = *(const s8v*)&Bs[(ct * 4 + ks) * 512 + lane * 8];
      acc0[ct] = __builtin_amdgcn_mfma_f32_16x16x32_bf16(a0, bhi, acc0[ct], 0, 0, 0);
      acc1[ct] = __builtin_amdgcn_mfma_f32_16x16x32_bf16(a1, bhi, acc1[ct], 0, 0, 0);
    }
  }
  float sskip = 0.f;
  if (MIX) sskip = 1.f / (1.f + __expf(-*skip_ptr));
#pragma unroll
  for (int rf = 0; rf < 2; ++rf) {
#pragma unroll
    for (int ct = 0; ct < 8; ++ct) {
      int col = ct * 16 + li;
      float bv = bias[col];
      f4v a = rf ? acc1[ct] : acc0[ct];
#pragma unroll
      for (int r = 0; r < 4; ++r) {
        int grow = row0 + rf * 16 + g * 4 + r;
        if (grow < M) {
          float v = a[r] + bv;
          size_t off = (size_t)grow * 128 + col;
          if constexpr (MIX) {
            float hprev = bf2f(Cout[off]);
            Cout[off] = f2bf(elu_f(sskip * v + (1.f - sskip) * hprev));
          } else {
            Cout[off] = f2bf(v);
          }
        }
      }
    }
  }
}

__device__ __forceinline__ void dev_gemm_kv(
    const ushort_t* __restrict__ A, const ushort_t* __restrict__ Bkv,
    const float* __restrict__ bias, ushort_t* __restrict__ kvout,
    int M, int bx, int ch, ushort_t* Bs) {
  for (int i = threadIdx.x; i < 2048; i += 256) {
    int kvh = i >> 10, j = i & 1023;
    const ushort_t* src = Bkv + (size_t)kvh * SLOT_ELEMS + ch * 8192 + j * 8;
    *(s8v*)&Bs[kvh * 8192 + j * 8] = *(const s8v*)src;
  }
  __syncthreads();
  const int lane = threadIdx.x & 63;
  const int wave = threadIdx.x >> 6;
  const int row0 = bx * 128 + wave * 32;
  const int g = lane >> 4, li = lane & 15;
  f4v acc0[8], acc1[8];                    // [0..3]=K, [4..7]=V
#pragma unroll
  for (int t = 0; t < 8; ++t) {
    acc0[t] = f4v{0.f, 0.f, 0.f, 0.f};
    acc1[t] = f4v{0.f, 0.f, 0.f, 0.f};
  }
  int ar0 = row0 + li;       if (ar0 >= M) ar0 = M - 1;
  int ar1 = row0 + 16 + li;  if (ar1 >= M) ar1 = M - 1;
#pragma unroll
  for (int ks = 0; ks < 4; ++ks) {
    s8v a0, a1;
    load_a2(A, ar0, ar1, ks, g, a0, a1);
#pragma unroll
    for (int t = 0; t < 4; ++t) {
      s8v kh = *(const s8v*)&Bs[(t * 4 + ks) * 512 + lane * 8];
      acc0[t] = __builtin_amdgcn_mfma_f32_16x16x32_bf16(a0, kh, acc0[t], 0, 0, 0);
      acc1[t] = __builtin_amdgcn_mfma_f32_16x16x32_bf16(a1, kh, acc1[t], 0, 0, 0);
      s8v vh = *(const s8v*)&Bs[8192 + (t * 4 + ks) * 512 + lane * 8];
      acc0[4 + t] = __builtin_amdgcn_mfma_f32_16x16x32_bf16(a0, vh, acc0[4 + t], 0, 0, 0);
      acc1[4 + t] = __builtin_amdgcn_mfma_f32_16x16x32_bf16(a1, vh, acc1[4 + t], 0, 0, 0);
    }
  }
#pragma unroll
  for (int rf = 0; rf < 2; ++rf) {
#pragma unroll
    for (int t = 0; t < 4; ++t) {
      int col = ch * 64 + t * 16 + li;
      float bk = bias[col], bv = bias[128 + col];
#pragma unroll
      for (int r = 0; r < 4; ++r) {
        int grow = row0 + rf * 16 + g * 4 + r;
        if (grow < M) {
          float kvl = rf ? acc1[t][r] : acc0[t][r];
          float vvl = rf ? acc1[4 + t][r] : acc0[4 + t][r];
          ushort2 o;
          o.x = f2bf(kvl + bk);
          o.y = f2bf(vvl + bv);
          *(ushort2*)(kvout + (size_t)grow * 256 + 2 * col) = o;
        }
      }
    }
  }
}

// fp32-A proj body: bf16-rounded A and B (2 MFMAs/tile-pair); 32KB Bs
__device__ __forceinline__ void dev_proj(
    const float* __restrict__ A, const ushort_t* __restrict__ Bhi,
    const float* __restrict__ bias, ushort_t* __restrict__ Cout,
    int M, int bx, ushort_t* Bs) {
  for (int i = threadIdx.x; i < 2048; i += 256)
    *(s8v*)&Bs[i * 8] = *(const s8v*)(Bhi + (size_t)i * 8);
  __syncthreads();
  const int lane = threadIdx.x & 63;
  const int wave = threadIdx.x >> 6;
  const int row0 = bx * 128 + wave * 32;
  const int g = lane >> 4, li = lane & 15;
  f4v acc0[8], acc1[8];
#pragma unroll
  for (int ct = 0; ct < 8; ++ct) {
    acc0[ct] = f4v{0.f, 0.f, 0.f, 0.f};
    acc1[ct] = f4v{0.f, 0.f, 0.f, 0.f};
  }
  int ar0 = row0 + li;       if (ar0 >= M) ar0 = M - 1;
  int ar1 = row0 + 16 + li;  if (ar1 >= M) ar1 = M - 1;
#pragma unroll
  for (int ks = 0; ks < 4; ++ks) {
    s8v ahi[2];
#pragma unroll
    for (int rf = 0; rf < 2; ++rf) {
      int ar = rf ? ar1 : ar0;
      const float* ap = A + (size_t)ar * 128 + ks * 32 + g * 4;
      float4 u0 = *(const float4*)ap;
      float4 u1 = *(const float4*)(ap + 16);
      float x[8] = {u0.x, u0.y, u0.z, u0.w, u1.x, u1.y, u1.z, u1.w};
#pragma unroll
      for (int i = 0; i < 8; ++i) ahi[rf][i] = (short)f2bf(x[i]);
    }
#pragma unroll
    for (int ct = 0; ct < 8; ++ct) {
      s8v bhi = *(const s8v*)&Bs[(ct * 4 + ks) * 512 + lane * 8];
      acc0[ct] = __builtin_amdgcn_mfma_f32_16x16x32_bf16(ahi[0], bhi, acc0[ct], 0, 0, 0);
      acc1[ct] = __builtin_amdgcn_mfma_f32_16x16x32_bf16(ahi[1], bhi, acc1[ct], 0, 0, 0);
    }
  }
#pragma unroll
  for (int rf = 0; rf < 2; ++rf) {
#pragma unroll
    for (int ct = 0; ct < 8; ++ct) {
      int col = ct * 16 + li;
      float bv = bias[col];
      f4v a = rf ? acc1[ct] : acc0[ct];
#pragma unroll
      for (int r = 0; r < 4; ++r) {
        int grow = row0 + rf * 16 + g * 4 + r;
        if (grow < M) Cout[(size_t)grow * 128 + col] = f2bf(a[r] + bv);
      }
    }
  }
}

// ============ attention body: merged stream, 2 dst/wave, UN-deep ladder =========
// SEL: per-edge p_rel select by arena row (row>=NA -> cites).
template<bool SEL, int UN>
__device__ __forceinline__ void dev_attn_m(
    const int* __restrict__ rp, const int* __restrict__ col,
    const ushort_t* __restrict__ kv, const ushort_t* __restrict__ q,
    float prW, float prC, ushort_t* __restrict__ aggout, int ablk) {
  int lane = threadIdx.x & 63;
  int wave = threadIdx.x >> 6;
  int half = lane >> 5;
  int l32  = lane & 31;
  int dst  = ablk * 8 + wave * 2 + half;   // ndst % 8 == 0: no tail
  ushort4 qv = *(const ushort4*)(q + (size_t)dst * D + l32 * 4);
  float q0 = bf2f(qv.x), q1 = bf2f(qv.y), q2 = bf2f(qv.z), q3 = bf2f(qv.w);
  int e0 = rp[dst];
  int dt = rp[dst + 1] - e0;
  float z = 0.f, a0 = 0.f, a1 = 0.f, a2 = 0.f, a3 = 0.f;
  for (int jj = 0; jj < dt; jj += UN) {
    int4 us[UN]; bool vs[UN]; float prs[UN];
#pragma unroll
    for (int s2 = 0; s2 < UN; ++s2) {
      int idx = jj + s2;
      bool v = idx < dt;
      int ci = e0 + (v ? idx : 0);
      int row = col[ci];
      us[s2] = *(const int4*)(kv + (size_t)row * 256 + l32 * 8);
      vs[s2] = v;
      prs[s2] = SEL ? ((row >= NA) ? prC : prW) : prW;
    }
#pragma unroll
    for (int s2 = 0; s2 < UN; ++s2) {
      float p = q0 * klo(us[s2].x) + q1 * klo(us[s2].y)
              + q2 * klo(us[s2].z) + q3 * klo(us[s2].w);
      p += __shfl_xor(p, 1);
      p += __shfl_xor(p, 2);
      p += __shfl_xor(p, 4);
      float e = vs[s2] ? __expf(p * prs[s2]) : 0.f;
      z  += e;
      a0 += e * vhi(us[s2].x);
      a1 += e * vhi(us[s2].y);
      a2 += e * vhi(us[s2].z);
      a3 += e * vhi(us[s2].w);
    }
  }
  float inv = 1.f / (z + 1e-16f);
  ushort4 o;
  o.x = f2bf(a0 * inv);
  o.y = f2bf(a1 * inv);
  o.z = f2bf(a2 * inv);
  o.w = f2bf(a3 * inv);
  *(ushort4*)(aggout + (size_t)dst * D + l32 * 4) = o;
}

// ============ device CSR-build bodies ===========================================
__device__ __forceinline__ void dev_count(const int* __restrict__ dst,
                                          int* __restrict__ deg, int bidx) {
  for (int e = bidx * 256 + (int)threadIdx.x; e < E; e += 256 * 256)
    atomicAdd(&deg[dst[e]], 1);
}
__device__ __forceinline__ void dev_fill(const int* __restrict__ ei,
                                         const int* __restrict__ rp,
                                         int* __restrict__ cnt,
                                         int* __restrict__ col, int bidx, int off) {
  const int* dst = ei + E;
  for (int e = bidx * 256 + (int)threadIdx.x; e < E; e += 256 * 256) {
    int d = dst[e];
    int pos = atomicAdd(&cnt[d], 1);
    col[rp[d] + pos] = ei[e] + off;
  }
}

// =============== global kernels =================================================
// fusedProj: proj_a || proj_p || count (3-way interleave: b%3==2 -> count)
__global__ __launch_bounds__(256, 4) void fusedProj(
    const float* __restrict__ x_a, const float* __restrict__ x_p,
    const ushort_t* __restrict__ B0h, const ushort_t* __restrict__ B1h,
    const float* __restrict__ proj_b,
    ushort_t* __restrict__ h_a, ushort_t* __restrict__ h_p,
    const int* __restrict__ ei_w, const int* __restrict__ ei_c,
    const int* __restrict__ ei_r, int* __restrict__ degz) {
  __shared__ ushort_t Bs[16384];
  unsigned b = blockIdx.x;
  if (b % 3 == 2) {
    int ci = b / 3;
    if (ci < 768) {
      int rel = ci >> 8, sub = ci & 255;
      const int* dst = rel == 0 ? ei_w + E : rel == 1 ? ei_c + E : ei_r + E;
      int* deg = (rel == 2) ? (degz + NPP) : degz;   // deg_p merged; deg_a second
      dev_count(dst, deg, sub);
    }
  } else {
    int gi = b - (b + 1) / 3;
    if (gi < GB2c) dev_proj(x_a, B0h, proj_b,     h_a, NA,  gi, Bs);
    else           dev_proj(x_p, B1h, proj_b + D, h_p, NPP, gi - GB2c, Bs);
  }
}

// bigGEMM slices: s0 q_a | s1 q_p | s2,3 kv_rev | s4,5 kvW->arena[0,NA) | s6,7 kvC->arena[NA,..)
__device__ __forceinline__ void dev_biggemm_slice(
    int slice, int bx,
    const ushort_t* h_a, const ushort_t* h_p,
    const ushort_t* Bqa, const ushort_t* Bqp,
    const ushort_t* BkvR, const ushort_t* BkvW, const ushort_t* BkvC,
    const float* bqa, const float* bqp,
    const float* cbR, const float* cbW, const float* cbC,
    ushort_t* b_q, ushort_t* b_q2,
    ushort_t* kvR, ushort_t* kvP, ushort_t* Bs) {
  if (slice == 0)      dev_gemm8<false, false>(h_a, Bqa, bqa, b_q,  nullptr, NA,  bx, Bs);
  else if (slice == 1) dev_gemm8<false, false>(h_p, Bqp, bqp, b_q2, nullptr, NPP, bx, Bs);
  else if (slice <= 3) dev_gemm_kv(h_p, BkvR, cbR, kvR, NPP, bx, slice - 2, Bs);
  else if (slice <= 5) dev_gemm_kv(h_a, BkvW, cbW, kvP, NA,  bx, slice - 4, Bs);
  else                 dev_gemm_kv(h_p, BkvC, cbC, kvP + (size_t)NA * 256, NPP, bx, slice - 6, Bs);
}

__global__ __launch_bounds__(256, 4) void biggemm(
    const ushort_t* __restrict__ h_a, const ushort_t* __restrict__ h_p,
    const ushort_t* __restrict__ Bqa, const ushort_t* __restrict__ Bqp,
    const ushort_t* __restrict__ BkvR, const ushort_t* __restrict__ BkvW,
    const ushort_t* __restrict__ BkvC,
    const float* __restrict__ bqa, const float* __restrict__ bqp,
    const float* __restrict__ cbR, const float* __restrict__ cbW,
    const float* __restrict__ cbC,
    ushort_t* __restrict__ b_q, ushort_t* __restrict__ b_q2,
    ushort_t* __restrict__ kvR, ushort_t* __restrict__ kvP) {
  __shared__ ushort_t Bs[16384];
  dev_biggemm_slice(blockIdx.y, blockIdx.x, h_a, h_p, Bqa, Bqp, BkvR, BkvW, BkvC,
                    bqa, bqp, cbR, cbW, cbC, b_q, b_q2, kvR, kvP, Bs);
}

// fusedFill (layer 0): biggemm || fill (768 blocks), 9-way interleave
__global__ __launch_bounds__(256, 4) void fusedFill(
    const ushort_t* __restrict__ h_a, const ushort_t* __restrict__ h_p,
    const ushort_t* __restrict__ Bqa, const ushort_t* __restrict__ Bqp,
    const ushort_t* __restrict__ BkvR, const ushort_t* __restrict__ BkvW,
    const ushort_t* __restrict__ BkvC,
    const float* __restrict__ bqa, const float* __restrict__ bqp,
    const float* __restrict__ cbR, const float* __restrict__ cbW,
    const float* __restrict__ cbC,
    ushort_t* __restrict__ b_q, ushort_t* __restrict__ b_q2,
    ushort_t* __restrict__ kvR, ushort_t* __restrict__ kvP,
    const int* __restrict__ ei_w, const int* __restrict__ ei_c,
    const int* __restrict__ ei_r,
    const int* __restrict__ rp_p, const int* __restrict__ rp_r,
    int* __restrict__ cntz, int* __restrict__ col_p, int* __restrict__ col_r) {
  __shared__ ushort_t Bs[16384];
  unsigned b = blockIdx.x;
  if (b % 9 == 8) {
    int fi = b / 9;
    if (fi < 768) {
      int rel = fi >> 8, sub = fi & 255;
      if (rel == 0)      dev_fill(ei_w, rp_p, cntz,       col_p, sub, 0);
      else if (rel == 1) dev_fill(ei_c, rp_p, cntz,       col_p, sub, NA);
      else               dev_fill(ei_r, rp_r, cntz + NPP, col_r, sub, 0);
    }
  } else {
    int gi = b - (b + 1) / 9;
    int slice = gi & 7, bx = gi >> 3;
    if (bx < GB2c)
      dev_biggemm_slice(slice, bx, h_a, h_p, Bqa, Bqp, BkvR, BkvW, BkvC,
                        bqa, bqp, cbR, cbW, cbC, b_q, b_q2, kvR, kvP, Bs);
  }
}

// bigATTN: parity-interleaved author (odd, 4-deep) + paper (even, 8-deep)
__global__ __launch_bounds__(256, 8) void bigattn(
    const int* __restrict__ rp_r, const int* __restrict__ col_r,
    const ushort_t* __restrict__ kvR, ushort_t* __restrict__ q_a,
    const int* __restrict__ rp_p, const int* __restrict__ col_p,
    const ushort_t* __restrict__ kvP, ushort_t* __restrict__ q_p,
    const float* __restrict__ prelR, const float* __restrict__ prelW,
    const float* __restrict__ prelC) {
  unsigned x = blockIdx.x;
  int head = (threadIdx.x & 31) >> 3;
  const float scale = 0.17677669529663688f; // 1/sqrt(32)
  if (x & 1) {
    float pr = prelR[head] * scale;
    dev_attn_m<false, 4>(rp_r, col_r, kvR, q_a, pr, pr, q_a, (int)(x >> 1));
  } else {
    dev_attn_m<true, 8>(rp_p, col_p, kvP, q_p,
                        prelW[head] * scale, prelC[head] * scale, q_p, (int)(x >> 1));
  }
}

// bigMIX: y0 author out-mix | y1 paper out-mix
__global__ __launch_bounds__(256, 4) void bigmix(
    const ushort_t* __restrict__ agg_a, const ushort_t* __restrict__ Bo0,
    const float* __restrict__ ob0, ushort_t* __restrict__ h_a,
    const float* __restrict__ sk0,
    const ushort_t* __restrict__ agg_p, const ushort_t* __restrict__ Bo1,
    const float* __restrict__ ob1, ushort_t* __restrict__ h_p,
    const float* __restrict__ sk1) {
  __shared__ ushort_t Bs[16384];
  if (blockIdx.y == 0) dev_gemm8<true, true>(agg_a, Bo0, ob0, h_a, sk0, NA,  blockIdx.x, Bs);
  else                 dev_gemm8<true, true>(agg_p, Bo1, ob1, h_p, sk1, NPP, blockIdx.x, Bs);
}

// cls: bf16 A, B hi/lo, fp32 out, 3 col tiles (40 cols)
__global__ __launch_bounds__(256, 4) void gemm_cls(
    const ushort_t* __restrict__ A,
    const ushort_t* __restrict__ Bhi, const ushort_t* __restrict__ Blo,
    const float* __restrict__ bias, float* __restrict__ Cv, int M) {
  constexpr int NT16 = 3;
  constexpr int HN = NT16 * 2048;
  __shared__ ushort_t Bs[HN * 2];
  for (int i = threadIdx.x; i < (HN / 8) * 2; i += 256) {
    int half = i / (HN / 8), j = i % (HN / 8);
    const ushort_t* src = (half ? Blo : Bhi) + (size_t)j * 8;
    *(s8v*)&Bs[half * HN + j * 8] = *(const s8v*)src;
  }
  __syncthreads();
  const int lane = threadIdx.x & 63;
  const int wave = threadIdx.x >> 6;
  const int row0 = blockIdx.x * 128 + wave * 32;
  const int g = lane >> 4, li = lane & 15;
  f4v acc0[NT16], acc1[NT16];
#pragma unroll
  for (int ct = 0; ct < NT16; ++ct) {
    acc0[ct] = f4v{0.f, 0.f, 0.f, 0.f};
    acc1[ct] = f4v{0.f, 0.f, 0.f, 0.f};
  }
  int ar0 = row0 + li;       if (ar0 >= M) ar0 = M - 1;
  int ar1 = row0 + 16 + li;  if (ar1 >= M) ar1 = M - 1;
#pragma unroll
  for (int ks = 0; ks < 4; ++ks) {
    s8v a0, a1;
    load_a2(A, ar0, ar1, ks, g, a0, a1);
#pragma unroll
    for (int ct = 0; ct < NT16; ++ct) {
      const ushort_t* bp = &Bs[(ct * 4 + ks) * 512 + lane * 8];
      s8v bhi = *(const s8v*)bp;
      s8v blo = *(const s8v*)(bp + HN);
      acc0[ct] = __builtin_amdgcn_mfma_f32_16x16x32_bf16(a0, bhi, acc0[ct], 0, 0, 0);
      acc1[ct] = __builtin_amdgcn_mfma_f32_16x16x32_bf16(a1, bhi, acc1[ct], 0, 0, 0);
      acc0[ct] = __builtin_amdgcn_mfma_f32_16x16x32_bf16(a0, blo, acc0[ct], 0, 0, 0);
      acc1[ct] = __builtin_amdgcn_mfma_f32_16x16x32_bf16(a1, blo, acc1[ct], 0, 0, 0);
    }
  }
#pragma unroll
  for (int rf = 0; rf < 2; ++rf) {
#pragma unroll
    for (int ct = 0; ct < NT16; ++ct) {
      int col = ct * 16 + li;
      bool colok = (col < 40);
      float bv = colok ? bias[col] : 0.f;
      f4v a = rf ? acc1[ct] : acc0[ct];
#pragma unroll
      for (int r = 0; r < 4; ++r) {
        int grow = row0 + rf * 16 + g * 4 + r;
        if (grow < M && colok) Cv[(size_t)grow * 40 + col] = a[r] + bv;
      }
    }
  }
}

// ------------- combined weights: cw = W @ blockdiag(rel), cb = b @ blockdiag(rel)
__global__ __launch_bounds__(256) void combine_w(
    const float* __restrict__ kqv_w, const float* __restrict__ kqv_b,
    const float* __restrict__ rel_a, const float* __restrict__ rel_m,
    float* __restrict__ cw, float* __restrict__ cb) {
  int b  = blockIdx.x;            // ((l*R)+r)*2+kv
  int kv = b & 1;
  int r  = (b >> 1) % R;
  int l  = b / (2 * R);
  int t_src = (r == 0) ? 0 : 1;
  int i_w   = (kv == 0) ? 0 : 2;
  const float* W    = kqv_w + ((size_t)((l*3 + i_w)*2 + t_src)) * D * D;
  const float* bvec = kqv_b + ((size_t)((l*3 + i_w)*2 + t_src)) * D;
  const float* rel  = ((kv == 0) ? rel_a : rel_m) + ((size_t)(l*R + r)) * H * 32 * 32;
  float* Cout = cw + (size_t)b * D * D;
  float* cbo  = cb + (size_t)b * D;
  for (int idx = threadIdx.x; idx < D * D; idx += 256) {
    int i = idx / D, j = idx % D;
    int h = j >> 5, f = j & 31;
    const float* relh = rel + h * 32 * 32;
    float sum = 0.f;
#pragma unroll
    for (int d = 0; d < 32; ++d) sum += W[i*D + (h*32 + d)] * relh[d*32 + f];
    Cout[idx] = sum;
  }
  if (threadIdx.x < D) {
    int j = threadIdx.x;
    int h = j >> 5, f = j & 31;
    const float* relh = rel + h * 32 * 32;
    float sum = 0.f;
#pragma unroll
    for (int d = 0; d < 32; ++d) sum += bvec[h*32 + d] * relh[d*32 + f];
    cbo[j] = sum;
  }
}

// ------------- pack weight matrices into MFMA-fragment order (hi/lo split) -------
__global__ __launch_bounds__(256) void pack_b(
    const float* __restrict__ proj_w, const float* __restrict__ kqv_w,
    const float* __restrict__ out_w, const float* __restrict__ cls_w,
    const float* __restrict__ cw,
    ushort_t* __restrict__ phi, ushort_t* __restrict__ plo) {
  int slot = blockIdx.x;
  const float* src; int ncol = 128;
  if (slot == 0) src = proj_w;
  else if (slot == 1) src = proj_w + D * D;
  else if (slot == 22) { src = cls_w; ncol = 40; }
  else {
    int l = (slot - 2) / 10, k = (slot - 2) % 10;
    if (k == 0)      src = kqv_w + ((size_t)((l*3 + 1)*2 + 0)) * D * D;
    else if (k == 1) src = kqv_w + ((size_t)((l*3 + 1)*2 + 1)) * D * D;
    else if (k < 8)  { int idx = k - 2; src = cw + ((size_t)((l*R)*2 + idx)) * D * D; }
    else             src = out_w + ((size_t)(l*2 + (k - 8))) * D * D;
  }
  int nt = (ncol + 15) / 16;
  int total = nt * 4 * 512;
  ushort_t* ph = phi + (size_t)slot * SLOT_ELEMS;
  ushort_t* pl = plo + (size_t)slot * SLOT_ELEMS;
  for (int idx = threadIdx.x; idx < total; idx += 256) {
    int j = idx & 7, lane = (idx >> 3) & 63, ks = (idx >> 9) & 3, ct = idx >> 11;
    int k = 4 * (lane >> 4) + (j & 3) + 16 * (j >> 2) + 32 * ks;
    int n = ct * 16 + (lane & 15);
    float v = (n < ncol) ? src[(size_t)k * ncol + n] : 0.f;
    unsigned short h = f2bf(v);
    ph[idx] = h;
    pl[idx] = f2bf(v - bf2f(h));
  }
}

// ---------------- scans (2 arrays: deg_p, deg_a; 50 blocks) ---------------------
__global__ __launch_bounds__(256) void scan_partial(const int* __restrict__ degz,
                                                    int* __restrict__ bsum) {
  int blk = blockIdx.x, rel = blk / 25, t25 = blk % 25;
  const int* deg = degz + rel * NPP + t25 * 4096;
  int nrem = min(4096, NPP - t25 * 4096);
  int base = threadIdx.x * 16;
  int s = 0;
  if (base < nrem) {
#pragma unroll
    for (int i4 = 0; i4 < 4; ++i4) {
      int4 v = *(const int4*)(deg + base + i4 * 4);
      s += v.x + v.y + v.z + v.w;
    }
  }
  __shared__ int sm[256];
  sm[threadIdx.x] = s; __syncthreads();
  for (int o = 128; o > 0; o >>= 1) {
    if (threadIdx.x < o) sm[threadIdx.x] += sm[threadIdx.x + o];
    __syncthreads();
  }
  if (threadIdx.x == 0) bsum[blk] = sm[0];
}
__global__ __launch_bounds__(256) void scan_final(const int* __restrict__ degz,
                                                  const int* __restrict__ bsum,
                                                  int* rp_p, int* rp_r) {
  int blk = blockIdx.x, rel = blk / 25, t25 = blk % 25;
  const int* deg = degz + rel * NPP + t25 * 4096;
  int* rpb = (rel == 0 ? rp_p : rp_r);
  int* rp = rpb + t25 * 4096;
  int boffv = 0;
  for (int i = 0; i < t25; ++i) boffv += bsum[rel * 25 + i];
  int nrem = min(4096, NPP - t25 * 4096);
  int base = threadIdx.x * 16;
  bool ok = base < nrem;
  int v[16]; int s = 0;
  if (ok) {
#pragma unroll
    for (int i4 = 0; i4 < 4; ++i4) {
      int4 u = *(const int4*)(deg + base + i4 * 4);
      v[i4*4+0] = u.x; v[i4*4+1] = u.y; v[i4*4+2] = u.z; v[i4*4+3] = u.w;
      s += u.x + u.y + u.z + u.w;
    }
  }
  __shared__ int sm[256];
  sm[threadIdx.x] = s; __syncthreads();
  for (int o = 1; o < 256; o <<= 1) {
    int x = (threadIdx.x >= o) ? sm[threadIdx.x - o] : 0;
    __syncthreads(); sm[threadIdx.x] += x; __syncthreads();
  }
  int run = boffv + sm[threadIdx.x] - s;
  if (ok) {
    int w[16];
#pragma unroll
    for (int i = 0; i < 16; ++i) { w[i] = run; run += v[i]; }
#pragma unroll
    for (int i4 = 0; i4 < 4; ++i4) *(int4*)(rp + base + i4 * 4) = *(const int4*)&w[i4*4];
  }
  if (t25 == 24 && threadIdx.x == 255) rpb[NPP] = boffv + sm[255];
}

extern "C" void kernel_launch(void* const* d_in, const int* in_sizes, int n_in,
                              void* d_out, int out_size, void* d_ws, size_t ws_size,
                              hipStream_t stream) {
  const float* x_a    = (const float*)d_in[0];
  const float* x_p    = (const float*)d_in[1];
  const int*   ei_w   = (const int*)d_in[2];
  const int*   ei_r   = (const int*)d_in[3];
  const int*   ei_c   = (const int*)d_in[4];
  const float* proj_w = (const float*)d_in[5];
  const float* proj_b = (const float*)d_in[6];
  const float* kqv_w  = (const float*)d_in[7];
  const float* kqv_b  = (const float*)d_in[8];
  const float* out_w  = (const float*)d_in[9];
  const float* out_b  = (const float*)d_in[10];
  const float* rel_a  = (const float*)d_in[11];
  const float* rel_m  = (const float*)d_in[12];
  const float* p_rel  = (const float*)d_in[13];
  const float* skip   = (const float*)d_in[14];
  const float* cls_w  = (const float*)d_in[15];
  const float* cls_b  = (const float*)d_in[16];
  float* out = (float*)d_out;

  const size_t NF = (size_t)NA * D;   // 12.8M
  char* p = (char*)d_ws;
  float* cw = (float*)p;              p += (size_t)12 * D * D * 4;
  float* cb = (float*)p;              p += (size_t)12 * D * 4;
  ushort_t* h_a   = (ushort_t*)p;     p += NF * 2;
  ushort_t* h_p   = (ushort_t*)p;     p += NF * 2;
  ushort_t* b_q   = (ushort_t*)p;     p += NF * 2;
  ushort_t* b_q2  = (ushort_t*)p;     p += NF * 2;
  ushort_t* b_kvR = (ushort_t*)p;     p += 2 * NF * 2;
  ushort_t* b_kvP = (ushort_t*)p;     p += 4 * NF * 2;   // arena: [0,NA) writes; [NA,..) cites
  ushort_t* phi = (ushort_t*)p;       p += (size_t)NSLOT * SLOT_ELEMS * 2;
  ushort_t* plo = (ushort_t*)p;       p += (size_t)NSLOT * SLOT_ELEMS * 2;
  int* rp_p = (int*)p;                p += (NPP + 1) * 4;
  int* rp_r = (int*)p;                p += (NA + 1) * 4;
  int* degz = (int*)p;                p += (size_t)2 * NPP * 4;   // deg_p, deg_a
  int* cntz = (int*)p;                p += (size_t)2 * NPP * 4;   // cnt_p, cnt_a
  int* col_p = (int*)p;               p += (size_t)2 * E * 4;
  int* col_r = (int*)p;               p += (size_t)E * 4;
  int* bsum = (int*)p;                p += 128 * 4;
  if (ws_size < (size_t)(p - (char*)d_ws)) return;   // graceful fail

  hipMemsetAsync(degz, 0, sizeof(int) * 4 * (size_t)NPP, stream);

  combine_w<<<12, 256, 0, stream>>>(kqv_w, kqv_b, rel_a, rel_m, cw, cb);
  pack_b<<<NSLOT, 256, 0, stream>>>(proj_w, kqv_w, out_w, cls_w, cw, phi, plo);

  auto PH = [&](int s){ return phi + (size_t)s * SLOT_ELEMS; };
  auto PL = [&](int s){ return plo + (size_t)s * SLOT_ELEMS; };

  // proj_a || proj_p || count  (2346 blocks, 3-way interleave)
  fusedProj<<<2346, 256, 0, stream>>>(
      x_a, x_p, PH(0), PH(1), proj_b, h_a, h_p,
      ei_w, ei_c, ei_r, degz);
  scan_partial<<<50, 256, 0, stream>>>(degz, bsum);
  scan_final<<<50, 256, 0, stream>>>(degz, bsum, rp_p, rp_r);

  for (int l = 0; l < L; ++l) {
    const int SQA = 2 + l * 10 + 0, SQP = 2 + l * 10 + 1;
    auto SKV = [&](int r){ return 2 + l * 10 + 2 + r * 2; };
    const int SO0 = 2 + l * 10 + 8, SO1 = 2 + l * 10 + 9;
    const float* bq_a = kqv_b + ((size_t)((l*3 + 1)*2 + 0)) * D;
    const float* bq_p = kqv_b + ((size_t)((l*3 + 1)*2 + 1)) * D;
    auto CB2 = [&](int r){ return cb + ((size_t)((l*R + r)*2)) * D; };
    const float* prelW = p_rel + (size_t)(l*R + 0) * H;
    const float* prelR = p_rel + (size_t)(l*R + 1) * H;
    const float* prelC = p_rel + (size_t)(l*R + 2) * H;

    if (l == 0) {
      fusedFill<<<7038, 256, 0, stream>>>(
          h_a, h_p, PH(SQA), PH(SQP), PH(SKV(1)), PH(SKV(0)), PH(SKV(2)),
          bq_a, bq_p, CB2(1), CB2(0), CB2(2),
          b_q, b_q2, b_kvR, b_kvP,
          ei_w, ei_c, ei_r, rp_p, rp_r, cntz, col_p, col_r);
    } else {
      biggemm<<<dim3(GB2c, 8), 256, 0, stream>>>(
          h_a, h_p, PH(SQA), PH(SQP), PH(SKV(1)), PH(SKV(0)), PH(SKV(2)),
          bq_a, bq_p, CB2(1), CB2(0), CB2(2),
          b_q, b_q2, b_kvR, b_kvP);
    }
    bigattn<<<2 * GAc, 256, 0, stream>>>(
        rp_r, col_r, b_kvR, b_q,
        rp_p, col_p, b_kvP, b_q2,
        prelR, prelW, prelC);
    bigmix<<<dim3(GB2c, 2), 256, 0, stream>>>(
        b_q,  PH(SO0), out_b + (size_t)(l*2 + 0) * D, h_a, skip + l*2 + 0,
        b_q2, PH(SO1), out_b + (size_t)(l*2 + 1) * D, h_p, skip + l*2 + 1);
  }

  gemm_cls<<<dim3(GB2c, 1), 256, 0, stream>>>(
      h_p, PH(22), PL(22), cls_b, out, NPP);
}

// Round 18
// 768.110 us; speedup vs baseline: 1.2816x; 1.2816x over previous
//
#include <hip/hip_runtime.h>
#include <hip/hip_bf16.h>
#include <math.h>

constexpr int NA  = 100000;
constexpr int NPP = 100000;
constexpr int D   = 128;
constexpr int H   = 4;
constexpr int E   = 400000;
constexpr int R   = 3;
constexpr int L   = 2;
constexpr int NSLOT = 23;
constexpr int SLOT_ELEMS = 8 * 4 * 512;   // 8 col-tiles * 4 ksteps * 512 bf16
constexpr int GB2c = (NA + 127) / 128;    // 782
constexpr int GAc  = NA / 8;              // 12500

using s8v = __attribute__((ext_vector_type(8))) short;
using f4v = __attribute__((ext_vector_type(4))) float;
typedef unsigned short ushort_t;

static __device__ __forceinline__ unsigned short f2bf(float f) {
  unsigned u = __float_as_uint(f);
  return (unsigned short)((u + 0x7fffu + ((u >> 16) & 1u)) >> 16);
}
static __device__ __forceinline__ float bf2f(unsigned short s) {
  return __uint_as_float(((unsigned)s) << 16);
}
static __device__ __forceinline__ float klo(int i) {        // low bf16 -> f32
  return __uint_as_float(((unsigned)i) << 16);
}
static __device__ __forceinline__ float vhi(int i) {        // high bf16 -> f32
  return __uint_as_float(((unsigned)i) & 0xffff0000u);
}
static __device__ __forceinline__ float gelu_f(float x) {
  return 0.5f * x * (1.0f + erff(x * 0.70710678118654752f));
}
static __device__ __forceinline__ float elu_f(float x) {
  return x > 0.0f ? x : expm1f(x);
}

// ============ device GEMM bodies (bf16 A, hi-only B, LDS-staged) ================
static __device__ __forceinline__ void load_a2(
    const ushort_t* __restrict__ A, int ar0, int ar1, int ks, int g,
    s8v& a0, s8v& a1) {
  const ushort_t* ap0 = A + (size_t)ar0 * 128 + ks * 32 + g * 4;
  ushort4 u0 = *(const ushort4*)ap0;
  ushort4 u1 = *(const ushort4*)(ap0 + 16);
  a0[0]=(short)u0.x; a0[1]=(short)u0.y; a0[2]=(short)u0.z; a0[3]=(short)u0.w;
  a0[4]=(short)u1.x; a0[5]=(short)u1.y; a0[6]=(short)u1.z; a0[7]=(short)u1.w;
  const ushort_t* ap1 = A + (size_t)ar1 * 128 + ks * 32 + g * 4;
  ushort4 v0 = *(const ushort4*)ap1;
  ushort4 v1 = *(const ushort4*)(ap1 + 16);
  a1[0]=(short)v0.x; a1[1]=(short)v0.y; a1[2]=(short)v0.z; a1[3]=(short)v0.w;
  a1[4]=(short)v1.x; a1[5]=(short)v1.y; a1[6]=(short)v1.z; a1[7]=(short)v1.w;
}

template<bool GELU_A, bool MIX>
__device__ __forceinline__ void dev_gemm8(
    const ushort_t* __restrict__ A, const ushort_t* __restrict__ Bhi,
    const float* __restrict__ bias, ushort_t* __restrict__ Cout,
    const float* __restrict__ skip_ptr, int M, int bx, ushort_t* Bs) {
  for (int i = threadIdx.x; i < 2048; i += 256)
    *(s8v*)&Bs[i * 8] = *(const s8v*)(Bhi + (size_t)i * 8);
  __syncthreads();
  const int lane = threadIdx.x & 63;
  const int wave = threadIdx.x >> 6;
  const int row0 = bx * 128 + wave * 32;
  const int g = lane >> 4, li = lane & 15;
  f4v acc0[8], acc1[8];
#pragma unroll
  for (int ct = 0; ct < 8; ++ct) {
    acc0[ct] = f4v{0.f, 0.f, 0.f, 0.f};
    acc1[ct] = f4v{0.f, 0.f, 0.f, 0.f};
  }
  int ar0 = row0 + li;       if (ar0 >= M) ar0 = M - 1;
  int ar1 = row0 + 16 + li;  if (ar1 >= M) ar1 = M - 1;
#pragma unroll
  for (int ks = 0; ks < 4; ++ks) {
    s8v a0, a1;
    load_a2(A, ar0, ar1, ks, g, a0, a1);
    if (GELU_A) {
#pragma unroll
      for (int i = 0; i < 8; ++i) {
        a0[i] = (short)f2bf(gelu_f(bf2f((unsigned short)a0[i])));
        a1[i] = (short)f2bf(gelu_f(bf2f((unsigned short)a1[i])));
      }
    }
#pragma unroll
    for (int ct = 0; ct < 8; ++ct) {
      s8v bhi = *(const s8v*)&Bs[(ct * 4 + ks) * 512 + lane * 8];
      acc0[ct] = __builtin_amdgcn_mfma_f32_16x16x32_bf16(a0, bhi, acc0[ct], 0, 0, 0);
      acc1[ct] = __builtin_amdgcn_mfma_f32_16x16x32_bf16(a1, bhi, acc1[ct], 0, 0, 0);
    }
  }
  float sskip = 0.f;
  if (MIX) sskip = 1.f / (1.f + __expf(-*skip_ptr));
#pragma unroll
  for (int rf = 0; rf < 2; ++rf) {
#pragma unroll
    for (int ct = 0; ct < 8; ++ct) {
      int col = ct * 16 + li;
      float bv = bias[col];
      f4v a = rf ? acc1[ct] : acc0[ct];
#pragma unroll
      for (int r = 0; r < 4; ++r) {
        int grow = row0 + rf * 16 + g * 4 + r;
        if (grow < M) {
          float v = a[r] + bv;
          size_t off = (size_t)grow * 128 + col;
          if constexpr (MIX) {
            float hprev = bf2f(Cout[off]);
            Cout[off] = f2bf(elu_f(sskip * v + (1.f - sskip) * hprev));
          } else {
            Cout[off] = f2bf(v);
          }
        }
      }
    }
  }
}

__device__ __forceinline__ void dev_gemm_kv(
    const ushort_t* __restrict__ A, const ushort_t* __restrict__ Bkv,
    const float* __restrict__ bias, ushort_t* __restrict__ kvout,
    int M, int bx, int ch, ushort_t* Bs) {
  for (int i = threadIdx.x; i < 2048; i += 256) {
    int kvh = i >> 10, j = i & 1023;
    const ushort_t* src = Bkv + (size_t)kvh * SLOT_ELEMS + ch * 8192 + j * 8;
    *(s8v*)&Bs[kvh * 8192 + j * 8] = *(const s8v*)src;
  }
  __syncthreads();
  const int lane = threadIdx.x & 63;
  const int wave = threadIdx.x >> 6;
  const int row0 = bx * 128 + wave * 32;
  const int g = lane >> 4, li = lane & 15;
  f4v acc0[8], acc1[8];                    // [0..3]=K, [4..7]=V
#pragma unroll
  for (int t = 0; t < 8; ++t) {
    acc0[t] = f4v{0.f, 0.f, 0.f, 0.f};
    acc1[t] = f4v{0.f, 0.f, 0.f, 0.f};
  }
  int ar0 = row0 + li;       if (ar0 >= M) ar0 = M - 1;
  int ar1 = row0 + 16 + li;  if (ar1 >= M) ar1 = M - 1;
#pragma unroll
  for (int ks = 0; ks < 4; ++ks) {
    s8v a0, a1;
    load_a2(A, ar0, ar1, ks, g, a0, a1);
#pragma unroll
    for (int t = 0; t < 4; ++t) {
      s8v kh = *(const s8v*)&Bs[(t * 4 + ks) * 512 + lane * 8];
      acc0[t] = __builtin_amdgcn_mfma_f32_16x16x32_bf16(a0, kh, acc0[t], 0, 0, 0);
      acc1[t] = __builtin_amdgcn_mfma_f32_16x16x32_bf16(a1, kh, acc1[t], 0, 0, 0);
      s8v vh = *(const s8v*)&Bs[8192 + (t * 4 + ks) * 512 + lane * 8];
      acc0[4 + t] = __builtin_amdgcn_mfma_f32_16x16x32_bf16(a0, vh, acc0[4 + t], 0, 0, 0);
      acc1[4 + t] = __builtin_amdgcn_mfma_f32_16x16x32_bf16(a1, vh, acc1[4 + t], 0, 0, 0);
    }
  }
#pragma unroll
  for (int rf = 0; rf < 2; ++rf) {
#pragma unroll
    for (int t = 0; t < 4; ++t) {
      int col = ch * 64 + t * 16 + li;
      float bk = bias[col], bv = bias[128 + col];
#pragma unroll
      for (int r = 0; r < 4; ++r) {
        int grow = row0 + rf * 16 + g * 4 + r;
        if (grow < M) {
          float kvl = rf ? acc1[t][r] : acc0[t][r];
          float vvl = rf ? acc1[4 + t][r] : acc0[4 + t][r];
          ushort2 o;
          o.x = f2bf(kvl + bk);
          o.y = f2bf(vvl + bv);
          *(ushort2*)(kvout + (size_t)grow * 256 + 2 * col) = o;
        }
      }
    }
  }
}

// fp32-A proj body: bf16-rounded A and B (2 MFMAs/tile-pair); 32KB Bs
__device__ __forceinline__ void dev_proj(
    const float* __restrict__ A, const ushort_t* __restrict__ Bhi,
    const float* __restrict__ bias, ushort_t* __restrict__ Cout,
    int M, int bx, ushort_t* Bs) {
  for (int i = threadIdx.x; i < 2048; i += 256)
    *(s8v*)&Bs[i * 8] = *(const s8v*)(Bhi + (size_t)i * 8);
  __syncthreads();
  const int lane = threadIdx.x & 63;
  const int wave = threadIdx.x >> 6;
  const int row0 = bx * 128 + wave * 32;
  const int g = lane >> 4, li = lane & 15;
  f4v acc0[8], acc1[8];
#pragma unroll
  for (int ct = 0; ct < 8; ++ct) {
    acc0[ct] = f4v{0.f, 0.f, 0.f, 0.f};
    acc1[ct] = f4v{0.f, 0.f, 0.f, 0.f};
  }
  int ar0 = row0 + li;       if (ar0 >= M) ar0 = M - 1;
  int ar1 = row0 + 16 + li;  if (ar1 >= M) ar1 = M - 1;
#pragma unroll
  for (int ks = 0; ks < 4; ++ks) {
    s8v ahi[2];
#pragma unroll
    for (int rf = 0; rf < 2; ++rf) {
      int ar = rf ? ar1 : ar0;
      const float* ap = A + (size_t)ar * 128 + ks * 32 + g * 4;
      float4 u0 = *(const float4*)ap;
      float4 u1 = *(const float4*)(ap + 16);
      float x[8] = {u0.x, u0.y, u0.z, u0.w, u1.x, u1.y, u1.z, u1.w};
#pragma unroll
      for (int i = 0; i < 8; ++i) ahi[rf][i] = (short)f2bf(x[i]);
    }
#pragma unroll
    for (int ct = 0; ct < 8; ++ct) {
      s8v bhi = *(const s8v*)&Bs[(ct * 4 + ks) * 512 + lane * 8];
      acc0[ct] = __builtin_amdgcn_mfma_f32_16x16x32_bf16(ahi[0], bhi, acc0[ct], 0, 0, 0);
      acc1[ct] = __builtin_amdgcn_mfma_f32_16x16x32_bf16(ahi[1], bhi, acc1[ct], 0, 0, 0);
    }
  }
#pragma unroll
  for (int rf = 0; rf < 2; ++rf) {
#pragma unroll
    for (int ct = 0; ct < 8; ++ct) {
      int col = ct * 16 + li;
      float bv = bias[col];
      f4v a = rf ? acc1[ct] : acc0[ct];
#pragma unroll
      for (int r = 0; r < 4; ++r) {
        int grow = row0 + rf * 16 + g * 4 + r;
        if (grow < M) Cout[(size_t)grow * 128 + col] = f2bf(a[r] + bv);
      }
    }
  }
}

// ============ attention body: merged stream, 2 dst/wave, 4-deep ladder ==========
// SEL: per-edge p_rel select by arena row (row>=NA -> cites).
// (4-deep measured optimal: 8-deep thrashes L2 — round 17 regression.)
template<bool SEL>
__device__ __forceinline__ void dev_attn_m(
    const int* __restrict__ rp, const int* __restrict__ col,
    const ushort_t* __restrict__ kv, const ushort_t* __restrict__ q,
    float prW, float prC, ushort_t* __restrict__ aggout, int ablk) {
  int lane = threadIdx.x & 63;
  int wave = threadIdx.x >> 6;
  int half = lane >> 5;
  int l32  = lane & 31;
  int dst  = ablk * 8 + wave * 2 + half;   // ndst % 8 == 0: no tail
  ushort4 qv = *(const ushort4*)(q + (size_t)dst * D + l32 * 4);
  float q0 = bf2f(qv.x), q1 = bf2f(qv.y), q2 = bf2f(qv.z), q3 = bf2f(qv.w);
  int e0 = rp[dst];
  int dt = rp[dst + 1] - e0;
  float z = 0.f, a0 = 0.f, a1 = 0.f, a2 = 0.f, a3 = 0.f;
  for (int jj = 0; jj < dt; jj += 4) {
    int4 us[4]; bool vs[4]; float prs[4];
#pragma unroll
    for (int s2 = 0; s2 < 4; ++s2) {
      int idx = jj + s2;
      bool v = idx < dt;
      int ci = e0 + (v ? idx : 0);
      int row = col[ci];
      us[s2] = *(const int4*)(kv + (size_t)row * 256 + l32 * 8);
      vs[s2] = v;
      prs[s2] = SEL ? ((row >= NA) ? prC : prW) : prW;
    }
#pragma unroll
    for (int s2 = 0; s2 < 4; ++s2) {
      float p = q0 * klo(us[s2].x) + q1 * klo(us[s2].y)
              + q2 * klo(us[s2].z) + q3 * klo(us[s2].w);
      p += __shfl_xor(p, 1);
      p += __shfl_xor(p, 2);
      p += __shfl_xor(p, 4);
      float e = vs[s2] ? __expf(p * prs[s2]) : 0.f;
      z  += e;
      a0 += e * vhi(us[s2].x);
      a1 += e * vhi(us[s2].y);
      a2 += e * vhi(us[s2].z);
      a3 += e * vhi(us[s2].w);
    }
  }
  float inv = 1.f / (z + 1e-16f);
  ushort4 o;
  o.x = f2bf(a0 * inv);
  o.y = f2bf(a1 * inv);
  o.z = f2bf(a2 * inv);
  o.w = f2bf(a3 * inv);
  *(ushort4*)(aggout + (size_t)dst * D + l32 * 4) = o;
}

// ============ device CSR-build bodies ===========================================
__device__ __forceinline__ void dev_count(const int* __restrict__ dst,
                                          int* __restrict__ deg, int bidx) {
  for (int e = bidx * 256 + (int)threadIdx.x; e < E; e += 256 * 256)
    atomicAdd(&deg[dst[e]], 1);
}
__device__ __forceinline__ void dev_fill(const int* __restrict__ ei,
                                         const int* __restrict__ rp,
                                         int* __restrict__ cnt,
                                         int* __restrict__ col, int bidx, int off) {
  const int* dst = ei + E;
  for (int e = bidx * 256 + (int)threadIdx.x; e < E; e += 256 * 256) {
    int d = dst[e];
    int pos = atomicAdd(&cnt[d], 1);
    col[rp[d] + pos] = ei[e] + off;
  }
}

// =============== global kernels =================================================
// fusedProj: proj_a || proj_p || count (3-way interleave: b%3==2 -> count)
__global__ __launch_bounds__(256, 4) void fusedProj(
    const float* __restrict__ x_a, const float* __restrict__ x_p,
    const ushort_t* __restrict__ B0h, const ushort_t* __restrict__ B1h,
    const float* __restrict__ proj_b,
    ushort_t* __restrict__ h_a, ushort_t* __restrict__ h_p,
    const int* __restrict__ ei_w, const int* __restrict__ ei_c,
    const int* __restrict__ ei_r, int* __restrict__ degz) {
  __shared__ ushort_t Bs[16384];
  unsigned b = blockIdx.x;
  if (b % 3 == 2) {
    int ci = b / 3;
    if (ci < 768) {
      int rel = ci >> 8, sub = ci & 255;
      const int* dst = rel == 0 ? ei_w + E : rel == 1 ? ei_c + E : ei_r + E;
      int* deg = (rel == 2) ? (degz + NPP) : degz;   // deg_p merged; deg_a second
      dev_count(dst, deg, sub);
    }
  } else {
    int gi = b - (b + 1) / 3;
    if (gi < GB2c) dev_proj(x_a, B0h, proj_b,     h_a, NA,  gi, Bs);
    else           dev_proj(x_p, B1h, proj_b + D, h_p, NPP, gi - GB2c, Bs);
  }
}

// bigGEMM slices: s0 q_a | s1 q_p | s2,3 kv_rev | s4,5 kvW->arena[0,NA) | s6,7 kvC->arena[NA,..)
__device__ __forceinline__ void dev_biggemm_slice(
    int slice, int bx,
    const ushort_t* h_a, const ushort_t* h_p,
    const ushort_t* Bqa, const ushort_t* Bqp,
    const ushort_t* BkvR, const ushort_t* BkvW, const ushort_t* BkvC,
    const float* bqa, const float* bqp,
    const float* cbR, const float* cbW, const float* cbC,
    ushort_t* b_q, ushort_t* b_q2,
    ushort_t* kvR, ushort_t* kvP, ushort_t* Bs) {
  if (slice == 0)      dev_gemm8<false, false>(h_a, Bqa, bqa, b_q,  nullptr, NA,  bx, Bs);
  else if (slice == 1) dev_gemm8<false, false>(h_p, Bqp, bqp, b_q2, nullptr, NPP, bx, Bs);
  else if (slice <= 3) dev_gemm_kv(h_p, BkvR, cbR, kvR, NPP, bx, slice - 2, Bs);
  else if (slice <= 5) dev_gemm_kv(h_a, BkvW, cbW, kvP, NA,  bx, slice - 4, Bs);
  else                 dev_gemm_kv(h_p, BkvC, cbC, kvP + (size_t)NA * 256, NPP, bx, slice - 6, Bs);
}

__global__ __launch_bounds__(256, 4) void biggemm(
    const ushort_t* __restrict__ h_a, const ushort_t* __restrict__ h_p,
    const ushort_t* __restrict__ Bqa, const ushort_t* __restrict__ Bqp,
    const ushort_t* __restrict__ BkvR, const ushort_t* __restrict__ BkvW,
    const ushort_t* __restrict__ BkvC,
    const float* __restrict__ bqa, const float* __restrict__ bqp,
    const float* __restrict__ cbR, const float* __restrict__ cbW,
    const float* __restrict__ cbC,
    ushort_t* __restrict__ b_q, ushort_t* __restrict__ b_q2,
    ushort_t* __restrict__ kvR, ushort_t* __restrict__ kvP) {
  __shared__ ushort_t Bs[16384];
  dev_biggemm_slice(blockIdx.y, blockIdx.x, h_a, h_p, Bqa, Bqp, BkvR, BkvW, BkvC,
                    bqa, bqp, cbR, cbW, cbC, b_q, b_q2, kvR, kvP, Bs);
}

// fusedFill (layer 0): biggemm || fill (768 blocks), 9-way interleave
__global__ __launch_bounds__(256, 4) void fusedFill(
    const ushort_t* __restrict__ h_a, const ushort_t* __restrict__ h_p,
    const ushort_t* __restrict__ Bqa, const ushort_t* __restrict__ Bqp,
    const ushort_t* __restrict__ BkvR, const ushort_t* __restrict__ BkvW,
    const ushort_t* __restrict__ BkvC,
    const float* __restrict__ bqa, const float* __restrict__ bqp,
    const float* __restrict__ cbR, const float* __restrict__ cbW,
    const float* __restrict__ cbC,
    ushort_t* __restrict__ b_q, ushort_t* __restrict__ b_q2,
    ushort_t* __restrict__ kvR, ushort_t* __restrict__ kvP,
    const int* __restrict__ ei_w, const int* __restrict__ ei_c,
    const int* __restrict__ ei_r,
    const int* __restrict__ rp_p, const int* __restrict__ rp_r,
    int* __restrict__ cntz, int* __restrict__ col_p, int* __restrict__ col_r) {
  __shared__ ushort_t Bs[16384];
  unsigned b = blockIdx.x;
  if (b % 9 == 8) {
    int fi = b / 9;
    if (fi < 768) {
      int rel = fi >> 8, sub = fi & 255;
      if (rel == 0)      dev_fill(ei_w, rp_p, cntz,       col_p, sub, 0);
      else if (rel == 1) dev_fill(ei_c, rp_p, cntz,       col_p, sub, NA);
      else               dev_fill(ei_r, rp_r, cntz + NPP, col_r, sub, 0);
    }
  } else {
    int gi = b - (b + 1) / 9;
    int slice = gi & 7, bx = gi >> 3;
    if (bx < GB2c)
      dev_biggemm_slice(slice, bx, h_a, h_p, Bqa, Bqp, BkvR, BkvW, BkvC,
                        bqa, bqp, cbR, cbW, cbC, b_q, b_q2, kvR, kvP, Bs);
  }
}

// bigATTN: parity-interleaved author (odd) + paper (even); both 4-deep
__global__ __launch_bounds__(256, 8) void bigattn(
    const int* __restrict__ rp_r, const int* __restrict__ col_r,
    const ushort_t* __restrict__ kvR, ushort_t* __restrict__ q_a,
    const int* __restrict__ rp_p, const int* __restrict__ col_p,
    const ushort_t* __restrict__ kvP, ushort_t* __restrict__ q_p,
    const float* __restrict__ prelR, const float* __restrict__ prelW,
    const float* __restrict__ prelC) {
  unsigned x = blockIdx.x;
  int head = (threadIdx.x & 31) >> 3;
  const float scale = 0.17677669529663688f; // 1/sqrt(32)
  if (x & 1) {
    float pr = prelR[head] * scale;
    dev_attn_m<false>(rp_r, col_r, kvR, q_a, pr, pr, q_a, (int)(x >> 1));
  } else {
    dev_attn_m<true>(rp_p, col_p, kvP, q_p,
                     prelW[head] * scale, prelC[head] * scale, q_p, (int)(x >> 1));
  }
}

// bigMIX: y0 author out-mix | y1 paper out-mix
__global__ __launch_bounds__(256, 4) void bigmix(
    const ushort_t* __restrict__ agg_a, const ushort_t* __restrict__ Bo0,
    const float* __restrict__ ob0, ushort_t* __restrict__ h_a,
    const float* __restrict__ sk0,
    const ushort_t* __restrict__ agg_p, const ushort_t* __restrict__ Bo1,
    const float* __restrict__ ob1, ushort_t* __restrict__ h_p,
    const float* __restrict__ sk1) {
  __shared__ ushort_t Bs[16384];
  if (blockIdx.y == 0) dev_gemm8<true, true>(agg_a, Bo0, ob0, h_a, sk0, NA,  blockIdx.x, Bs);
  else                 dev_gemm8<true, true>(agg_p, Bo1, ob1, h_p, sk1, NPP, blockIdx.x, Bs);
}

// cls: bf16 A, B hi/lo, fp32 out, 3 col tiles (40 cols)
__global__ __launch_bounds__(256, 4) void gemm_cls(
    const ushort_t* __restrict__ A,
    const ushort_t* __restrict__ Bhi, const ushort_t* __restrict__ Blo,
    const float* __restrict__ bias, float* __restrict__ Cv, int M) {
  constexpr int NT16 = 3;
  constexpr int HN = NT16 * 2048;
  __shared__ ushort_t Bs[HN * 2];
  for (int i = threadIdx.x; i < (HN / 8) * 2; i += 256) {
    int half = i / (HN / 8), j = i % (HN / 8);
    const ushort_t* src = (half ? Blo : Bhi) + (size_t)j * 8;
    *(s8v*)&Bs[half * HN + j * 8] = *(const s8v*)src;
  }
  __syncthreads();
  const int lane = threadIdx.x & 63;
  const int wave = threadIdx.x >> 6;
  const int row0 = blockIdx.x * 128 + wave * 32;
  const int g = lane >> 4, li = lane & 15;
  f4v acc0[NT16], acc1[NT16];
#pragma unroll
  for (int ct = 0; ct < NT16; ++ct) {
    acc0[ct] = f4v{0.f, 0.f, 0.f, 0.f};
    acc1[ct] = f4v{0.f, 0.f, 0.f, 0.f};
  }
  int ar0 = row0 + li;       if (ar0 >= M) ar0 = M - 1;
  int ar1 = row0 + 16 + li;  if (ar1 >= M) ar1 = M - 1;
#pragma unroll
  for (int ks = 0; ks < 4; ++ks) {
    s8v a0, a1;
    load_a2(A, ar0, ar1, ks, g, a0, a1);
#pragma unroll
    for (int ct = 0; ct < NT16; ++ct) {
      const ushort_t* bp = &Bs[(ct * 4 + ks) * 512 + lane * 8];
      s8v bhi = *(const s8v*)bp;
      s8v blo = *(const s8v*)(bp + HN);
      acc0[ct] = __builtin_amdgcn_mfma_f32_16x16x32_bf16(a0, bhi, acc0[ct], 0, 0, 0);
      acc1[ct] = __builtin_amdgcn_mfma_f32_16x16x32_bf16(a1, bhi, acc1[ct], 0, 0, 0);
      acc0[ct] = __builtin_amdgcn_mfma_f32_16x16x32_bf16(a0, blo, acc0[ct], 0, 0, 0);
      acc1[ct] = __builtin_amdgcn_mfma_f32_16x16x32_bf16(a1, blo, acc1[ct], 0, 0, 0);
    }
  }
#pragma unroll
  for (int rf = 0; rf < 2; ++rf) {
#pragma unroll
    for (int ct = 0; ct < NT16; ++ct) {
      int col = ct * 16 + li;
      bool colok = (col < 40);
      float bv = colok ? bias[col] : 0.f;
      f4v a = rf ? acc1[ct] : acc0[ct];
#pragma unroll
      for (int r = 0; r < 4; ++r) {
        int grow = row0 + rf * 16 + g * 4 + r;
        if (grow < M && colok) Cv[(size_t)grow * 40 + col] = a[r] + bv;
      }
    }
  }
}

// ------------- combined weights: cw = W @ blockdiag(rel), cb = b @ blockdiag(rel)
__global__ __launch_bounds__(256) void combine_w(
    const float* __restrict__ kqv_w, const float* __restrict__ kqv_b,
    const float* __restrict__ rel_a, const float* __restrict__ rel_m,
    float* __restrict__ cw, float* __restrict__ cb) {
  int b  = blockIdx.x;            // ((l*R)+r)*2+kv
  int kv = b & 1;
  int r  = (b >> 1) % R;
  int l  = b / (2 * R);
  int t_src = (r == 0) ? 0 : 1;
  int i_w   = (kv == 0) ? 0 : 2;
  const float* W    = kqv_w + ((size_t)((l*3 + i_w)*2 + t_src)) * D * D;
  const float* bvec = kqv_b + ((size_t)((l*3 + i_w)*2 + t_src)) * D;
  const float* rel  = ((kv == 0) ? rel_a : rel_m) + ((size_t)(l*R + r)) * H * 32 * 32;
  float* Cout = cw + (size_t)b * D * D;
  float* cbo  = cb + (size_t)b * D;
  for (int idx = threadIdx.x; idx < D * D; idx += 256) {
    int i = idx / D, j = idx % D;
    int h = j >> 5, f = j & 31;
    const float* relh = rel + h * 32 * 32;
    float sum = 0.f;
#pragma unroll
    for (int d = 0; d < 32; ++d) sum += W[i*D + (h*32 + d)] * relh[d*32 + f];
    Cout[idx] = sum;
  }
  if (threadIdx.x < D) {
    int j = threadIdx.x;
    int h = j >> 5, f = j & 31;
    const float* relh = rel + h * 32 * 32;
    float sum = 0.f;
#pragma unroll
    for (int d = 0; d < 32; ++d) sum += bvec[h*32 + d] * relh[d*32 + f];
    cbo[j] = sum;
  }
}

// ------------- pack weight matrices into MFMA-fragment order (hi/lo split) -------
__global__ __launch_bounds__(256) void pack_b(
    const float* __restrict__ proj_w, const float* __restrict__ kqv_w,
    const float* __restrict__ out_w, const float* __restrict__ cls_w,
    const float* __restrict__ cw,
    ushort_t* __restrict__ phi, ushort_t* __restrict__ plo) {
  int slot = blockIdx.x;
  const float* src; int ncol = 128;
  if (slot == 0) src = proj_w;
  else if (slot == 1) src = proj_w + D * D;
  else if (slot == 22) { src = cls_w; ncol = 40; }
  else {
    int l = (slot - 2) / 10, k = (slot - 2) % 10;
    if (k == 0)      src = kqv_w + ((size_t)((l*3 + 1)*2 + 0)) * D * D;
    else if (k == 1) src = kqv_w + ((size_t)((l*3 + 1)*2 + 1)) * D * D;
    else if (k < 8)  { int idx = k - 2; src = cw + ((size_t)((l*R)*2 + idx)) * D * D; }
    else             src = out_w + ((size_t)(l*2 + (k - 8))) * D * D;
  }
  int nt = (ncol + 15) / 16;
  int total = nt * 4 * 512;
  ushort_t* ph = phi + (size_t)slot * SLOT_ELEMS;
  ushort_t* pl = plo + (size_t)slot * SLOT_ELEMS;
  for (int idx = threadIdx.x; idx < total; idx += 256) {
    int j = idx & 7, lane = (idx >> 3) & 63, ks = (idx >> 9) & 3, ct = idx >> 11;
    int k = 4 * (lane >> 4) + (j & 3) + 16 * (j >> 2) + 32 * ks;
    int n = ct * 16 + (lane & 15);
    float v = (n < ncol) ? src[(size_t)k * ncol + n] : 0.f;
    unsigned short h = f2bf(v);
    ph[idx] = h;
    pl[idx] = f2bf(v - bf2f(h));
  }
}

// ---------------- scans (2 arrays: deg_p, deg_a; 50 blocks) ---------------------
__global__ __launch_bounds__(256) void scan_partial(const int* __restrict__ degz,
                                                    int* __restrict__ bsum) {
  int blk = blockIdx.x, rel = blk / 25, t25 = blk % 25;
  const int* deg = degz + rel * NPP + t25 * 4096;
  int nrem = min(4096, NPP - t25 * 4096);
  int base = threadIdx.x * 16;
  int s = 0;
  if (base < nrem) {
#pragma unroll
    for (int i4 = 0; i4 < 4; ++i4) {
      int4 v = *(const int4*)(deg + base + i4 * 4);
      s += v.x + v.y + v.z + v.w;
    }
  }
  __shared__ int sm[256];
  sm[threadIdx.x] = s; __syncthreads();
  for (int o = 128; o > 0; o >>= 1) {
    if (threadIdx.x < o) sm[threadIdx.x] += sm[threadIdx.x + o];
    __syncthreads();
  }
  if (threadIdx.x == 0) bsum[blk] = sm[0];
}
__global__ __launch_bounds__(256) void scan_final(const int* __restrict__ degz,
                                                  const int* __restrict__ bsum,
                                                  int* rp_p, int* rp_r) {
  int blk = blockIdx.x, rel = blk / 25, t25 = blk % 25;
  const int* deg = degz + rel * NPP + t25 * 4096;
  int* rpb = (rel == 0 ? rp_p : rp_r);
  int* rp = rpb + t25 * 4096;
  int boffv = 0;
  for (int i = 0; i < t25; ++i) boffv += bsum[rel * 25 + i];
  int nrem = min(4096, NPP - t25 * 4096);
  int base = threadIdx.x * 16;
  bool ok = base < nrem;
  int v[16]; int s = 0;
  if (ok) {
#pragma unroll
    for (int i4 = 0; i4 < 4; ++i4) {
      int4 u = *(const int4*)(deg + base + i4 * 4);
      v[i4*4+0] = u.x; v[i4*4+1] = u.y; v[i4*4+2] = u.z; v[i4*4+3] = u.w;
      s += u.x + u.y + u.z + u.w;
    }
  }
  __shared__ int sm[256];
  sm[threadIdx.x] = s; __syncthreads();
  for (int o = 1; o < 256; o <<= 1) {
    int x = (threadIdx.x >= o) ? sm[threadIdx.x - o] : 0;
    __syncthreads(); sm[threadIdx.x] += x; __syncthreads();
  }
  int run = boffv + sm[threadIdx.x] - s;
  if (ok) {
    int w[16];
#pragma unroll
    for (int i = 0; i < 16; ++i) { w[i] = run; run += v[i]; }
#pragma unroll
    for (int i4 = 0; i4 < 4; ++i4) *(int4*)(rp + base + i4 * 4) = *(const int4*)&w[i4*4];
  }
  if (t25 == 24 && threadIdx.x == 255) rpb[NPP] = boffv + sm[255];
}

extern "C" void kernel_launch(void* const* d_in, const int* in_sizes, int n_in,
                              void* d_out, int out_size, void* d_ws, size_t ws_size,
                              hipStream_t stream) {
  const float* x_a    = (const float*)d_in[0];
  const float* x_p    = (const float*)d_in[1];
  const int*   ei_w   = (const int*)d_in[2];
  const int*   ei_r   = (const int*)d_in[3];
  const int*   ei_c   = (const int*)d_in[4];
  const float* proj_w = (const float*)d_in[5];
  const float* proj_b = (const float*)d_in[6];
  const float* kqv_w  = (const float*)d_in[7];
  const float* kqv_b  = (const float*)d_in[8];
  const float* out_w  = (const float*)d_in[9];
  const float* out_b  = (const float*)d_in[10];
  const float* rel_a  = (const float*)d_in[11];
  const float* rel_m  = (const float*)d_in[12];
  const float* p_rel  = (const float*)d_in[13];
  const float* skip   = (const float*)d_in[14];
  const float* cls_w  = (const float*)d_in[15];
  const float* cls_b  = (const float*)d_in[16];
  float* out = (float*)d_out;

  const size_t NF = (size_t)NA * D;   // 12.8M
  char* p = (char*)d_ws;
  float* cw = (float*)p;              p += (size_t)12 * D * D * 4;
  float* cb = (float*)p;              p += (size_t)12 * D * 4;
  ushort_t* h_a   = (ushort_t*)p;     p += NF * 2;
  ushort_t* h_p   = (ushort_t*)p;     p += NF * 2;
  ushort_t* b_q   = (ushort_t*)p;     p += NF * 2;
  ushort_t* b_q2  = (ushort_t*)p;     p += NF * 2;
  ushort_t* b_kvR = (ushort_t*)p;     p += 2 * NF * 2;
  ushort_t* b_kvP = (ushort_t*)p;     p += 4 * NF * 2;   // arena: [0,NA) writes; [NA,..) cites
  ushort_t* phi = (ushort_t*)p;       p += (size_t)NSLOT * SLOT_ELEMS * 2;
  ushort_t* plo = (ushort_t*)p;       p += (size_t)NSLOT * SLOT_ELEMS * 2;
  int* rp_p = (int*)p;                p += (NPP + 1) * 4;
  int* rp_r = (int*)p;                p += (NA + 1) * 4;
  int* degz = (int*)p;                p += (size_t)2 * NPP * 4;   // deg_p, deg_a
  int* cntz = (int*)p;                p += (size_t)2 * NPP * 4;   // cnt_p, cnt_a
  int* col_p = (int*)p;               p += (size_t)2 * E * 4;
  int* col_r = (int*)p;               p += (size_t)E * 4;
  int* bsum = (int*)p;                p += 128 * 4;
  if (ws_size < (size_t)(p - (char*)d_ws)) return;   // graceful fail

  hipMemsetAsync(degz, 0, sizeof(int) * 4 * (size_t)NPP, stream);

  combine_w<<<12, 256, 0, stream>>>(kqv_w, kqv_b, rel_a, rel_m, cw, cb);
  pack_b<<<NSLOT, 256, 0, stream>>>(proj_w, kqv_w, out_w, cls_w, cw, phi, plo);

  auto PH = [&](int s){ return phi + (size_t)s * SLOT_ELEMS; };
  auto PL = [&](int s){ return plo + (size_t)s * SLOT_ELEMS; };

  // proj_a || proj_p || count  (2346 blocks, 3-way interleave)
  fusedProj<<<2346, 256, 0, stream>>>(
      x_a, x_p, PH(0), PH(1), proj_b, h_a, h_p,
      ei_w, ei_c, ei_r, degz);
  scan_partial<<<50, 256, 0, stream>>>(degz, bsum);
  scan_final<<<50, 256, 0, stream>>>(degz, bsum, rp_p, rp_r);

  for (int l = 0; l < L; ++l) {
    const int SQA = 2 + l * 10 + 0, SQP = 2 + l * 10 + 1;
    auto SKV = [&](int r){ return 2 + l * 10 + 2 + r * 2; };
    const int SO0 = 2 + l * 10 + 8, SO1 = 2 + l * 10 + 9;
    const float* bq_a = kqv_b + ((size_t)((l*3 + 1)*2 + 0)) * D;
    const float* bq_p = kqv_b + ((size_t)((l*3 + 1)*2 + 1)) * D;
    auto CB2 = [&](int r){ return cb + ((size_t)((l*R + r)*2)) * D; };
    const float* prelW = p_rel + (size_t)(l*R + 0) * H;
    const float* prelR = p_rel + (size_t)(l*R + 1) * H;
    const float* prelC = p_rel + (size_t)(l*R + 2) * H;

    if (l == 0) {
      fusedFill<<<7038, 256, 0, stream>>>(
          h_a, h_p, PH(SQA), PH(SQP), PH(SKV(1)), PH(SKV(0)), PH(SKV(2)),
          bq_a, bq_p, CB2(1), CB2(0), CB2(2),
          b_q, b_q2, b_kvR, b_kvP,
          ei_w, ei_c, ei_r, rp_p, rp_r, cntz, col_p, col_r);
    } else {
      biggemm<<<dim3(GB2c, 8), 256, 0, stream>>>(
          h_a, h_p, PH(SQA), PH(SQP), PH(SKV(1)), PH(SKV(0)), PH(SKV(2)),
          bq_a, bq_p, CB2(1), CB2(0), CB2(2),
          b_q, b_q2, b_kvR, b_kvP);
    }
    bigattn<<<2 * GAc, 256, 0, stream>>>(
        rp_r, col_r, b_kvR, b_q,
        rp_p, col_p, b_kvP, b_q2,
        prelR, prelW, prelC);
    bigmix<<<dim3(GB2c, 2), 256, 0, stream>>>(
        b_q,  PH(SO0), out_b + (size_t)(l*2 + 0) * D, h_a, skip + l*2 + 0,
        b_q2, PH(SO1), out_b + (size_t)(l*2 + 1) * D, h_p, skip + l*2 + 1);
  }

  gemm_cls<<<dim3(GB2c, 1), 256, 0, stream>>>(
      h_p, PH(22), PL(22), cls_b, out, NPP);
}